// Round 3
// baseline (58.955 us; speedup 1.0000x reference)
//
#include <hip/hip_runtime.h>

// Inverse 2x2 Haar reconstruction:
// out[n, 2h+j, 2w+i] = w2[i,0]*l_j + w2[i,1]*h_j
//   l_j = w1[j,0]*x[n,0,h,w] + w1[j,1]*x[n,1,h,w]
//   h_j = w1[j,0]*x[n,2,h,w] + w1[j,1]*x[n,3,h,w]
//
// R2: non-temporal output stores via native ext_vector_type (the builtin
// rejects HIP_vector_type). Goal: keep the 134 MB input L3-resident across
// replays so reads hit L3 and the kernel approaches the pure-write ceiling.

typedef float f32x4 __attribute__((ext_vector_type(4)));

constexpr int N_  = 32;
constexpr int S_  = 512;
constexpr int SS_ = S_ * S_;          // 262144 (one channel plane)
constexpr int W4_ = S_ / 4;           // 128 quads per row
constexpr int PER_N_ = S_ * W4_;      // 65536 work items per image
constexpr int TOTAL_ = N_ * PER_N_;   // 2097152 work items

__global__ __launch_bounds__(256)
void haar_recon_kernel(const float* __restrict__ x,
                       const float* __restrict__ w1,
                       const float* __restrict__ w2,
                       float* __restrict__ out) {
    int idx = blockIdx.x * 256 + threadIdx.x;
    if (idx >= TOTAL_) return;

    int n   = idx / PER_N_;
    int rem = idx - n * PER_N_;
    int h   = rem / W4_;
    int w   = (rem - h * W4_) * 4;

    const float w1_00 = w1[0], w1_01 = w1[1], w1_10 = w1[2], w1_11 = w1[3];
    const float w2_00 = w2[0], w2_01 = w2[1], w2_10 = w2[2], w2_11 = w2[3];

    const float* xb = x + (size_t)n * 4 * SS_ + h * S_ + w;
    f32x4 a0 = *(const f32x4*)(xb);            // channel 0 (t=0,k=0)
    f32x4 a1 = *(const f32x4*)(xb + SS_);      // channel 1 (t=0,k=1)
    f32x4 a2 = *(const f32x4*)(xb + 2 * SS_);  // channel 2 (t=1,k=0)
    f32x4 a3 = *(const f32x4*)(xb + 3 * SS_);  // channel 3 (t=1,k=1)

    f32x4 topA, topB, botA, botB;
    #pragma unroll
    for (int e = 0; e < 4; ++e) {
        float l0 = w1_00 * a0[e] + w1_01 * a1[e];   // j=0, low band
        float l1 = w1_10 * a0[e] + w1_11 * a1[e];   // j=1
        float h0 = w1_00 * a2[e] + w1_01 * a3[e];   // j=0, high band
        float h1 = w1_10 * a2[e] + w1_11 * a3[e];   // j=1

        float t0 = w2_00 * l0 + w2_01 * h0;   // (j=0, i=0)
        float t1 = w2_10 * l0 + w2_11 * h0;   // (j=0, i=1)
        float b0 = w2_00 * l1 + w2_01 * h1;   // (j=1, i=0)
        float b1 = w2_10 * l1 + w2_11 * h1;   // (j=1, i=1)

        if (e < 2) {
            topA[2 * e]     = t0;  topA[2 * e + 1] = t1;
            botA[2 * e]     = b0;  botA[2 * e + 1] = b1;
        } else {
            topB[2 * (e - 2)]     = t0;  topB[2 * (e - 2) + 1] = t1;
            botB[2 * (e - 2)]     = b0;  botB[2 * (e - 2) + 1] = b1;
        }
    }

    float* otop = out + (size_t)n * 4 * SS_ + (size_t)(2 * h) * (2 * S_) + 2 * w;
    float* obot = otop + 2 * S_;

    __builtin_nontemporal_store(topA, (f32x4*)(otop));
    __builtin_nontemporal_store(topB, (f32x4*)(otop + 4));
    __builtin_nontemporal_store(botA, (f32x4*)(obot));
    __builtin_nontemporal_store(botB, (f32x4*)(obot + 4));
}

extern "C" void kernel_launch(void* const* d_in, const int* in_sizes, int n_in,
                              void* d_out, int out_size, void* d_ws, size_t ws_size,
                              hipStream_t stream) {
    const float* x  = (const float*)d_in[0];
    const float* w1 = (const float*)d_in[1];
    const float* w2 = (const float*)d_in[2];
    float* out = (float*)d_out;

    int blocks = (TOTAL_ + 255) / 256;  // 8192
    haar_recon_kernel<<<blocks, 256, 0, stream>>>(x, w1, w2, out);
}

// Round 4
// 45.691 us; speedup vs baseline: 1.2903x; 1.2903x over previous
//
#include <hip/hip_runtime.h>

// Inverse 2x2 Haar reconstruction:
// out[n, 2h+j, 2w+i] = w2[i,0]*l_j + w2[i,1]*h_j
//   l_j = w1[j,0]*x[n,0,h,w] + w1[j,1]*x[n,1,h,w]
//   h_j = w1[j,0]*x[n,2,h,w] + w1[j,1]*x[n,3,h,w]
//
// R3: revert R2's non-temporal stores. Counters showed nt inflated
// WRITE_SIZE 131->177 MB (broken write-line combining) with no FETCH
// reduction -> 45.9us regressed to 59.0us. Plain cached float4 stores
// are the proven best: 268 MB logical at ~5.8 TB/s = ~93% of the
// achievable mixed-stream ceiling.

constexpr int N_  = 32;
constexpr int S_  = 512;
constexpr int SS_ = S_ * S_;          // 262144 (one channel plane)
constexpr int W4_ = S_ / 4;           // 128 quads per row
constexpr int PER_N_ = S_ * W4_;      // 65536 work items per image
constexpr int TOTAL_ = N_ * PER_N_;   // 2097152 work items

__global__ __launch_bounds__(256)
void haar_recon_kernel(const float* __restrict__ x,
                       const float* __restrict__ w1,
                       const float* __restrict__ w2,
                       float* __restrict__ out) {
    int idx = blockIdx.x * 256 + threadIdx.x;
    if (idx >= TOTAL_) return;

    int n   = idx / PER_N_;
    int rem = idx - n * PER_N_;
    int h   = rem / W4_;
    int w   = (rem - h * W4_) * 4;

    const float w1_00 = w1[0], w1_01 = w1[1], w1_10 = w1[2], w1_11 = w1[3];
    const float w2_00 = w2[0], w2_01 = w2[1], w2_10 = w2[2], w2_11 = w2[3];

    const float* xb = x + (size_t)n * 4 * SS_ + h * S_ + w;
    float4 a0 = *(const float4*)(xb);            // channel 0 (t=0,k=0)
    float4 a1 = *(const float4*)(xb + SS_);      // channel 1 (t=0,k=1)
    float4 a2 = *(const float4*)(xb + 2 * SS_);  // channel 2 (t=1,k=0)
    float4 a3 = *(const float4*)(xb + 3 * SS_);  // channel 3 (t=1,k=1)

    float c0[4] = {a0.x, a0.y, a0.z, a0.w};
    float c1[4] = {a1.x, a1.y, a1.z, a1.w};
    float c2[4] = {a2.x, a2.y, a2.z, a2.w};
    float c3[4] = {a3.x, a3.y, a3.z, a3.w};

    float top[8], bot[8];
    #pragma unroll
    for (int e = 0; e < 4; ++e) {
        float l0 = w1_00 * c0[e] + w1_01 * c1[e];   // j=0, low band
        float l1 = w1_10 * c0[e] + w1_11 * c1[e];   // j=1
        float h0 = w1_00 * c2[e] + w1_01 * c3[e];   // j=0, high band
        float h1 = w1_10 * c2[e] + w1_11 * c3[e];   // j=1

        top[2 * e]     = w2_00 * l0 + w2_01 * h0;   // (j=0, i=0)
        top[2 * e + 1] = w2_10 * l0 + w2_11 * h0;   // (j=0, i=1)
        bot[2 * e]     = w2_00 * l1 + w2_01 * h1;   // (j=1, i=0)
        bot[2 * e + 1] = w2_10 * l1 + w2_11 * h1;   // (j=1, i=1)
    }

    float* otop = out + (size_t)n * 4 * SS_ + (size_t)(2 * h) * (2 * S_) + 2 * w;
    float* obot = otop + 2 * S_;

    *(float4*)(otop)     = make_float4(top[0], top[1], top[2], top[3]);
    *(float4*)(otop + 4) = make_float4(top[4], top[5], top[6], top[7]);
    *(float4*)(obot)     = make_float4(bot[0], bot[1], bot[2], bot[3]);
    *(float4*)(obot + 4) = make_float4(bot[4], bot[5], bot[6], bot[7]);
}

extern "C" void kernel_launch(void* const* d_in, const int* in_sizes, int n_in,
                              void* d_out, int out_size, void* d_ws, size_t ws_size,
                              hipStream_t stream) {
    const float* x  = (const float*)d_in[0];
    const float* w1 = (const float*)d_in[1];
    const float* w2 = (const float*)d_in[2];
    float* out = (float*)d_out;

    int blocks = (TOTAL_ + 255) / 256;  // 8192
    haar_recon_kernel<<<blocks, 256, 0, stream>>>(x, w1, w2, out);
}